// Round 1
// baseline (277.121 us; speedup 1.0000x reference)
//
#include <hip/hip_runtime.h>
#include <stdint.h>

// ---------------------------------------------------------------------------
// CommNetActor fused forward, bf16x3 split-precision MFMA (gfx950).
//
//   rows = B*A = 262144; block = 256 thr (4 waves), owns 128 rows (32 batches)
//   LDS: X[128][132] f32 activations (in-place across layers), S (comm sums /
//        dec partials), Wb 32KB weight-fragment staging (hi/lo chunks).
//   Weights pre-converted once per launch into fragment-ordered hi/lo bf16 in
//   d_ws by prep_weights (needs 425,984 B of d_ws).
//   MFMA v_mfma_f32_32x32x16_bf16; D layout: col=lane&31,
//   row=(reg&3)+8*(reg>>2)+4*(lane>>5)  [HW-verified].
// ---------------------------------------------------------------------------

typedef __attribute__((ext_vector_type(4)))  float f32x4;
typedef __attribute__((ext_vector_type(16))) float f32x16;
typedef __attribute__((ext_vector_type(8)))  short bf16x8;

#define LDX     132          // padded leading dim of X/S tiles (floats)
#define WS_HALF 106496       // bf16 elements per (hi | lo) half of d_ws

__device__ __forceinline__ unsigned short bf16_rn(float f) {
  union { float f; uint32_t u; } v; v.f = f;
  uint32_t u = v.u;
  uint32_t r = (u + 0x7FFFu + ((u >> 16) & 1u)) >> 16;   // round-to-nearest-even
  return (unsigned short)r;
}
__device__ __forceinline__ float bf16_f32(unsigned short h) {
  union { uint32_t u; float f; } v; v.u = ((uint32_t)h) << 16;
  return v.f;
}
__device__ __forceinline__ f32x16 zero16() {
  f32x16 v;
#pragma unroll
  for (int i = 0; i < 16; ++i) v[i] = 0.0f;
  return v;
}
// split 8 f32 into hi/lo bf16 fragments
__device__ __forceinline__ void cvt_hilo(f32x4 a, f32x4 b, bf16x8& hi, bf16x8& lo) {
#pragma unroll
  for (int j = 0; j < 4; ++j) {
    unsigned short ha = bf16_rn(a[j]);
    unsigned short hb = bf16_rn(b[j]);
    hi[j]     = (short)ha;
    hi[j + 4] = (short)hb;
    lo[j]     = (short)bf16_rn(a[j] - bf16_f32(ha));
    lo[j + 4] = (short)bf16_rn(b[j] - bf16_f32(hb));
  }
}
__device__ __forceinline__ void cvt_hi(f32x4 a, f32x4 b, bf16x8& hi) {
#pragma unroll
  for (int j = 0; j < 4; ++j) {
    hi[j]     = (short)bf16_rn(a[j]);
    hi[j + 4] = (short)bf16_rn(b[j]);
  }
}

// barrier that drains LDS ops only — leaves prefetch global loads in flight
__device__ __forceinline__ void barrier_lds() {
  asm volatile("s_waitcnt lgkmcnt(0)\n\ts_barrier" ::: "memory");
}

// ---------------------------------------------------------------------------
// Pre-pass: convert all weights to MFMA-fragment-ordered hi/lo bf16.
// Fragment layout per matrix: [kc][nb][lane 0..63][j 0..7],
//   value = W[kc*16 + (lane>>5)*8 + j][nb*32 + (lane&31)]  (0-padded for dec)
// hi half at ws[0..WS_HALF), lo half at ws[WS_HALF..2*WS_HALF).
// Segment bases (bf16 elems): enc 0, fc1 8192, fc2 24576, fc3 40960,
//                             cl4 57344, dec 90112.
// ---------------------------------------------------------------------------
__global__ void prep_weights(const float* __restrict__ enc_w, const float* __restrict__ fc1_w,
                             const float* __restrict__ fc2_w, const float* __restrict__ fc3_w,
                             const float* __restrict__ cl4_w, const float* __restrict__ dec_w,
                             unsigned short* __restrict__ ws) {
  int idx = blockIdx.x * 256 + threadIdx.x;
  if (idx >= WS_HALF) return;
  const float* W; int base, N, nbN;
  if      (idx <  8192) { W = enc_w; base = 0;     N = 128; nbN = 4; }
  else if (idx < 24576) { W = fc1_w; base = 8192;  N = 128; nbN = 4; }
  else if (idx < 40960) { W = fc2_w; base = 24576; N = 128; nbN = 4; }
  else if (idx < 57344) { W = fc3_w; base = 40960; N = 128; nbN = 4; }
  else if (idx < 90112) { W = cl4_w; base = 57344; N = 128; nbN = 4; }
  else                  { W = dec_w; base = 90112; N = 16;  nbN = 1; }
  int local = idx - base;
  int j    = local & 7;
  int lane = (local >> 3) & 63;
  int frag = local >> 9;
  int nb = frag % nbN;
  int kc = frag / nbN;
  int k = kc * 16 + ((lane >> 5) << 3) + j;
  int n = nb * 32 + (lane & 31);
  float wv = (n < N) ? W[k * N + n] : 0.0f;
  unsigned short hi = bf16_rn(wv);
  ws[idx]           = hi;
  ws[WS_HALF + idx] = bf16_rn(wv - bf16_f32(hi));
}

// ---------------------------------------------------------------------------
// One fused layer: X[128][K] @ W[K][128] + b, activation, in-place into X.
// Wave grid 2x2: wave (wm,wn) computes rows [64wm,64wm+64) x cols [64wn,64wn+64)
// as 2x2 blocks of 32x32 MFMA tiles. Weight chunks (<=32KB) staged through Wb,
// register-prefetched one chunk ahead. Passes: hi (Ahi*Bhi + Alo*Bhi), then
// lo (Ahi*Blo). For cl4 (USES=true), k>=128 reads C=(S-H3)/4 on the fly.
// ---------------------------------------------------------------------------
template <int K, int ACT, bool USES>
__device__ __forceinline__ void layer_run(float* __restrict__ X, float* __restrict__ S,
                                          short* __restrict__ Wb,
                                          const unsigned short* __restrict__ whi,
                                          const unsigned short* __restrict__ wlo,
                                          const float* __restrict__ bias, int tid) {
  const int l  = tid & 63;
  const int w  = tid >> 6;
  const int wm = w >> 1, wn = w & 1;
  const int lr = l & 31;
  const int lh = l >> 5;
  constexpr int KC    = K / 16;           // 4 / 8 / 16
  constexpr int NCH   = (KC + 7) / 8;     // chunks per pass (1 or 2)
  constexpr int KCC   = KC / NCH;         // kc per chunk (4 or 8)
  constexpr int NST   = 2 * NCH;          // total staged chunks (hi then lo)
  constexpr int NKEEP = KC < 8 ? KC : 8;

  f32x16 acc[2][2];
#pragma unroll
  for (int mb = 0; mb < 2; ++mb)
#pragma unroll
    for (int nb = 0; nb < 2; ++nb) acc[mb][nb] = zero16();
  bf16x8 akeep[NKEEP][2];
  f32x4 pre[KCC];

  const int rowb = wm * 64 + lr;

  // prefetch chunk 0
  {
    const f32x4* gs = (const f32x4*)whi;
#pragma unroll
    for (int it = 0; it < KCC; ++it) pre[it] = gs[it * 256 + tid];
  }

#pragma unroll
  for (int c = 0; c < NST; ++c) {
    barrier_lds();   // Wb free (prev chunk consumed by all waves); X/S visible
    {
      f32x4* ds = (f32x4*)Wb;
#pragma unroll
      for (int it = 0; it < KCC; ++it) ds[it * 256 + tid] = pre[it];
    }
    if (c + 1 < NST) {   // issue next chunk's global loads (fly across barrier)
      const unsigned short* nsrc =
          (c + 1 < NCH) ? (whi + (c + 1) * KCC * 2048) : (wlo + (c + 1 - NCH) * KCC * 2048);
      const f32x4* gs = (const f32x4*)nsrc;
#pragma unroll
      for (int it = 0; it < KCC; ++it) pre[it] = gs[it * 256 + tid];
    }
    barrier_lds();   // chunk c staged
    if (c < NCH) {
      // ---- hi pass ----
#pragma unroll
      for (int kci = 0; kci < KCC; ++kci) {
        const int kc = c * KCC + kci;
        const int k0 = kc * 16 + lh * 8;
        bf16x8 ahi[2], alo[2];
#pragma unroll
        for (int mb = 0; mb < 2; ++mb) {
          const int row = rowb + mb * 32;
          f32x4 va, vb;
          if (!USES || kc < 8) {
            va = *(const f32x4*)&X[row * LDX + k0];
            vb = *(const f32x4*)&X[row * LDX + k0 + 4];
          } else {
            const int d0 = k0 - 128;
            const int bb = row >> 2;
            f32x4 s0 = *(const f32x4*)&S[bb * LDX + d0];
            f32x4 s1 = *(const f32x4*)&S[bb * LDX + d0 + 4];
            f32x4 h0 = *(const f32x4*)&X[row * LDX + d0];
            f32x4 h1 = *(const f32x4*)&X[row * LDX + d0 + 4];
            va = (s0 - h0) * 0.25f;
            vb = (s1 - h1) * 0.25f;
          }
          cvt_hilo(va, vb, ahi[mb], alo[mb]);
          if (kc < NKEEP) akeep[kc][mb] = ahi[mb];
        }
#pragma unroll
        for (int nb = 0; nb < 2; ++nb) {
          const bf16x8 bhi = *(const bf16x8*)&Wb[(kci * 4 + wn * 2 + nb) * 512 + l * 8];
#pragma unroll
          for (int mb = 0; mb < 2; ++mb) {
            acc[mb][nb] = __builtin_amdgcn_mfma_f32_32x32x16_bf16(ahi[mb], bhi, acc[mb][nb], 0, 0, 0);
            acc[mb][nb] = __builtin_amdgcn_mfma_f32_32x32x16_bf16(alo[mb], bhi, acc[mb][nb], 0, 0, 0);
          }
        }
      }
    } else {
      // ---- lo pass ----
      const int ch = c - NCH;
#pragma unroll
      for (int kci = 0; kci < KCC; ++kci) {
        const int kc = ch * KCC + kci;
        bf16x8 ahi[2];
#pragma unroll
        for (int mb = 0; mb < 2; ++mb) {
          if (kc < NKEEP) {
            ahi[mb] = akeep[kc][mb];
          } else {  // cl4 tail: recompute hi fragment from S/X
            const int k0 = kc * 16 + lh * 8;
            const int d0 = k0 - 128;
            const int row = rowb + mb * 32;
            const int bb = row >> 2;
            f32x4 s0 = *(const f32x4*)&S[bb * LDX + d0];
            f32x4 s1 = *(const f32x4*)&S[bb * LDX + d0 + 4];
            f32x4 h0 = *(const f32x4*)&X[row * LDX + d0];
            f32x4 h1 = *(const f32x4*)&X[row * LDX + d0 + 4];
            cvt_hi((s0 - h0) * 0.25f, (s1 - h1) * 0.25f, ahi[mb]);
          }
        }
#pragma unroll
        for (int nb = 0; nb < 2; ++nb) {
          const bf16x8 blo = *(const bf16x8*)&Wb[(kci * 4 + wn * 2 + nb) * 512 + l * 8];
#pragma unroll
          for (int mb = 0; mb < 2; ++mb)
            acc[mb][nb] = __builtin_amdgcn_mfma_f32_32x32x16_bf16(ahi[mb], blo, acc[mb][nb], 0, 0, 0);
        }
      }
    }
  }
  barrier_lds();  // all waves' X reads done -> in-place write is safe
  // epilogue: bias + activation, store D back into X
#pragma unroll
  for (int nb = 0; nb < 2; ++nb) {
    const float bv = bias[wn * 64 + nb * 32 + lr];
#pragma unroll
    for (int mb = 0; mb < 2; ++mb) {
#pragma unroll
      for (int r = 0; r < 16; ++r) {
        float vv = acc[mb][nb][r] + bv;
        if (ACT == 0)      vv = 1.0f / (1.0f + __expf(-vv));   // sigmoid
        else if (ACT == 1) vv = fmaxf(vv, 0.0f);               // relu
        const int row = wm * 64 + mb * 32 + ((r & 3) + 8 * (r >> 2) + 4 * lh);
        X[row * LDX + wn * 64 + nb * 32 + lr] = vv;
      }
    }
  }
}

// ---------------------------------------------------------------------------
__global__ __launch_bounds__(256, 1)
void commnet_fwd(const float* __restrict__ O,
                 const float* __restrict__ enc_b, const float* __restrict__ fc1_b,
                 const float* __restrict__ fc2_b, const float* __restrict__ fc3_b,
                 const float* __restrict__ cl4_b, const float* __restrict__ dec_b,
                 const unsigned short* __restrict__ ws, float* __restrict__ out) {
  __shared__ __attribute__((aligned(16))) float X[128 * LDX];  // 67,584 B
  __shared__ __attribute__((aligned(16))) float S[4224];       // 16,896 B
  __shared__ __attribute__((aligned(16))) short Wb[16384];     // 32,768 B

  const int tid = threadIdx.x;
  const int l  = tid & 63;
  const int w  = tid >> 6;
  const int lr = l & 31;
  const int lh = l >> 5;
  const long r0 = (long)blockIdx.x * 128;

  // ---- load O tile [128 x 64] into X cols 0..63 (coalesced float4) ----
  {
    const f32x4* Og = (const f32x4*)(O + r0 * 64);
#pragma unroll
    for (int it = 0; it < 8; ++it) {
      const int i = it * 256 + tid;
      const int row = i >> 4, c4 = i & 15;
      *(f32x4*)&X[row * LDX + c4 * 4] = Og[i];
    }
  }

  const unsigned short* wlo = ws + WS_HALF;
  layer_run<64,  0, false>(X, S, Wb, ws,          wlo,          enc_b, tid);
  layer_run<128, 1, false>(X, S, Wb, ws + 8192,   wlo + 8192,   fc1_b, tid);
  layer_run<128, 1, false>(X, S, Wb, ws + 24576,  wlo + 24576,  fc2_b, tid);
  layer_run<128, 1, false>(X, S, Wb, ws + 40960,  wlo + 40960,  fc3_b, tid);

  // ---- comm: S[b][d] = sum over 4 agents of H3 ----
  barrier_lds();
  {
    const int b = tid >> 3, dp = tid & 7;
#pragma unroll
    for (int q = 0; q < 4; ++q) {
      const int c = dp * 16 + q * 4;
      f32x4 s0 = *(const f32x4*)&X[(4 * b + 0) * LDX + c];
      f32x4 s1 = *(const f32x4*)&X[(4 * b + 1) * LDX + c];
      f32x4 s2 = *(const f32x4*)&X[(4 * b + 2) * LDX + c];
      f32x4 s3 = *(const f32x4*)&X[(4 * b + 3) * LDX + c];
      *(f32x4*)&S[b * LDX + c] = (s0 + s1) + (s2 + s3);
    }
  }
  // cl4: [H3 | (S-H3)/4](256) @ cl4_w, no activation
  layer_run<256, 2, true>(X, S, Wb, ws + 57344, wlo + 57344, cl4_b, tid);

  // ---- decoder: [32 batches x 512] @ dec_w(512x16->pad32) + softmax ----
  f32x16 dacc = zero16();
  bf16x8 dkeep[8];
  {
    const f32x4* ghi = (const f32x4*)(ws  + 90112);
    const f32x4* glo = (const f32x4*)(wlo + 90112);
    f32x4 t[8], t2[8];
#pragma unroll
    for (int it = 0; it < 8; ++it) t[it] = ghi[it * 256 + tid];
    barrier_lds();                       // cl4 done with Wb; H4 in X visible
    f32x4* ds = (f32x4*)Wb;
#pragma unroll
    for (int it = 0; it < 8; ++it) ds[it * 256 + tid] = t[it];
#pragma unroll
    for (int it = 0; it < 8; ++it) t2[it] = glo[it * 256 + tid];  // prefetch lo
    barrier_lds();                       // dec hi staged
    // pass1: each wave covers kc = w*8 .. w*8+7 (K split across waves)
#pragma unroll
    for (int k8 = 0; k8 < 8; ++k8) {
      const int kc = w * 8 + k8;
      const int k0 = kc * 16 + lh * 8;
      const int xrow = lr * 4 + (k0 >> 7);   // batch*4 + agent
      const int d = k0 & 127;
      f32x4 va = *(const f32x4*)&X[xrow * LDX + d];
      f32x4 vb = *(const f32x4*)&X[xrow * LDX + d + 4];
      bf16x8 ahi, alo;
      cvt_hilo(va, vb, ahi, alo);
      dkeep[k8] = ahi;
      const bf16x8 bhi = *(const bf16x8*)&Wb[kc * 512 + l * 8];
      dacc = __builtin_amdgcn_mfma_f32_32x32x16_bf16(ahi, bhi, dacc, 0, 0, 0);
      dacc = __builtin_amdgcn_mfma_f32_32x32x16_bf16(alo, bhi, dacc, 0, 0, 0);
    }
    barrier_lds();                       // hi reads done
#pragma unroll
    for (int it = 0; it < 8; ++it) ds[it * 256 + tid] = t2[it];
    barrier_lds();                       // dec lo staged
#pragma unroll
    for (int k8 = 0; k8 < 8; ++k8) {
      const int kc = w * 8 + k8;
      const bf16x8 blo = *(const bf16x8*)&Wb[kc * 512 + l * 8];
      dacc = __builtin_amdgcn_mfma_f32_32x32x16_bf16(dkeep[k8], blo, dacc, 0, 0, 0);
    }
  }
  // per-wave partials -> S as [w][32 rows][33]
#pragma unroll
  for (int r = 0; r < 16; ++r) {
    const int prow = (r & 3) + 8 * (r >> 2) + 4 * lh;
    S[w * 1056 + prow * 33 + lr] = dacc[r];
  }
  barrier_lds();
  // reduce 4 partials, bias, softmax, store (one thread per batch row)
  if (tid < 32) {
    const int b = tid;
    float lg[16];
#pragma unroll
    for (int c = 0; c < 16; ++c)
      lg[c] = S[b * 33 + c] + S[1056 + b * 33 + c] + S[2112 + b * 33 + c] +
              S[3168 + b * 33 + c] + dec_b[c];
    float m = lg[0];
#pragma unroll
    for (int c = 1; c < 16; ++c) m = fmaxf(m, lg[c]);
    float sum = 0.0f;
#pragma unroll
    for (int c = 0; c < 16; ++c) { lg[c] = __expf(lg[c] - m); sum += lg[c]; }
    const float inv = 1.0f / sum;
    float* op = out + ((long)blockIdx.x * 32 + b) * 16;
#pragma unroll
    for (int q = 0; q < 4; ++q) {
      f32x4 o = { lg[4 * q + 0] * inv, lg[4 * q + 1] * inv,
                  lg[4 * q + 2] * inv, lg[4 * q + 3] * inv };
      *(f32x4*)&op[q * 4] = o;
    }
  }
}

// ---------------------------------------------------------------------------
extern "C" void kernel_launch(void* const* d_in, const int* in_sizes, int n_in,
                              void* d_out, int out_size, void* d_ws, size_t ws_size,
                              hipStream_t stream) {
  (void)n_in; (void)out_size; (void)ws_size;  // needs ws_size >= 425,984 B
  const float* O     = (const float*)d_in[0];
  const float* enc_w = (const float*)d_in[1];
  const float* enc_b = (const float*)d_in[2];
  const float* fc1_w = (const float*)d_in[3];
  const float* fc1_b = (const float*)d_in[4];
  const float* fc2_w = (const float*)d_in[5];
  const float* fc2_b = (const float*)d_in[6];
  const float* fc3_w = (const float*)d_in[7];
  const float* fc3_b = (const float*)d_in[8];
  const float* cl4_w = (const float*)d_in[9];
  const float* cl4_b = (const float*)d_in[10];
  const float* dec_w = (const float*)d_in[11];
  const float* dec_b = (const float*)d_in[12];
  unsigned short* wsb = (unsigned short*)d_ws;

  prep_weights<<<(WS_HALF + 255) / 256, 256, 0, stream>>>(enc_w, fc1_w, fc2_w, fc3_w,
                                                          cl4_w, dec_w, wsb);
  const int rows   = in_sizes[0] / 64;   // B*A = 262144
  const int blocks = rows / 128;         // 2048
  commnet_fwd<<<blocks, 256, 0, stream>>>(O, enc_b, fc1_b, fc2_b, fc3_b, cl4_b,
                                          dec_b, wsb, (float*)d_out);
}

// Round 2
// 177.531 us; speedup vs baseline: 1.5610x; 1.5610x over previous
//
#include <hip/hip_runtime.h>
#include <stdint.h>

// ---------------------------------------------------------------------------
// CommNetActor fused forward v2 — bf16x3 split-precision MFMA (gfx950).
//
//  - 4096 blocks x 256 thr; block owns 64 rows (16 batches). LDS 57.6KB ->
//    2 blocks/CU (vs 1 before): cross-block overlap of barriers/compute.
//  - Activations live in LDS PRE-SPLIT as Xhi/Xlo bf16 (XOR-swizzled groups,
//    pitch 128): A-fragments are raw ds_read_b128, zero VALU in main loop.
//  - B-fragments stream L2->registers (frag-ordered in d_ws), double-buffered
//    one kc ahead; no Wb staging, no vmcnt-draining barriers (barrier_lds).
//  - Wave = column slice (w=0..3 -> cols w*32..+31): weights fetched once per
//    block; A-reads duplicated via cheap LDS.
//  - cl4 refactor: H_cat@W = H3@(Wtop - 0.25*Wbot) + S@(0.25*Wbot); the
//    S-GEMM is M=16 (one MFMA row-block), T added in cl4 epilogue.
//  - MFMA 32x32x16_bf16, D layout col=lane&31, row=(r&3)+8*(r>>2)+4*(lane>>5).
// ---------------------------------------------------------------------------

typedef __attribute__((ext_vector_type(4)))  float f32x4;
typedef __attribute__((ext_vector_type(16))) float f32x16;
typedef __attribute__((ext_vector_type(8)))  short bf16x8;
typedef __attribute__((ext_vector_type(4)))  short bf16x4;

#define WS_HALF 106496
// segment bases (bf16 elems) inside each half of d_ws
#define SEG_ENC 0
#define SEG_FC1 8192
#define SEG_FC2 24576
#define SEG_FC3 40960
#define SEG_W1  57344
#define SEG_W2  73728
#define SEG_DEC 90112

#define MFMA(a, b, c) __builtin_amdgcn_mfma_f32_32x32x16_bf16((a), (b), (c), 0, 0, 0)

__device__ __forceinline__ unsigned short bf16_rn(float f) {
  union { float f; uint32_t u; } v; v.f = f;
  uint32_t u = v.u;
  return (unsigned short)((u + 0x7FFFu + ((u >> 16) & 1u)) >> 16);
}
__device__ __forceinline__ float bf16_f32(unsigned short h) {
  union { uint32_t u; float f; } v; v.u = ((uint32_t)h) << 16;
  return v.f;
}
__device__ __forceinline__ void split1(float v, short& h, short& l) {
  unsigned short hh = bf16_rn(v);
  h = (short)hh;
  l = (short)bf16_rn(v - bf16_f32(hh));
}
__device__ __forceinline__ f32x16 zero16() {
  f32x16 v;
#pragma unroll
  for (int i = 0; i < 16; ++i) v[i] = 0.0f;
  return v;
}
// swizzled bf16 index: pitch 128, 16B groups XOR'd by row&15 (2-way max = free)
__device__ __forceinline__ int xswz(int row, int g) {
  return row * 128 + ((g ^ (row & 15)) << 3);
}
// barrier draining LDS only — register-bound global loads stay in flight
__device__ __forceinline__ void barrier_lds() {
  asm volatile("s_waitcnt lgkmcnt(0)\n\ts_barrier" ::: "memory");
}

// ---------------------------------------------------------------------------
// Weight prep: fragment-ordered hi/lo bf16. Frag f=(kc*nbN+nb):
//   value = W[kc*16 + (lane>>5)*8 + j][nb*32 + (lane&31)]
// cl4 split into W1 = Wtop - 0.25*Wbot and W2 = 0.25*Wbot. dec padded N16->32.
// ---------------------------------------------------------------------------
__global__ void prep_weights(const float* __restrict__ enc_w, const float* __restrict__ fc1_w,
                             const float* __restrict__ fc2_w, const float* __restrict__ fc3_w,
                             const float* __restrict__ cl4_w, const float* __restrict__ dec_w,
                             unsigned short* __restrict__ ws) {
  int idx = blockIdx.x * 256 + threadIdx.x;
  if (idx >= WS_HALF) return;
  const float* W; int base, N, nbN, mode;
  if      (idx <  8192) { W = enc_w; base = SEG_ENC; N = 128; nbN = 4; mode = 0; }
  else if (idx < 24576) { W = fc1_w; base = SEG_FC1; N = 128; nbN = 4; mode = 0; }
  else if (idx < 40960) { W = fc2_w; base = SEG_FC2; N = 128; nbN = 4; mode = 0; }
  else if (idx < 57344) { W = fc3_w; base = SEG_FC3; N = 128; nbN = 4; mode = 0; }
  else if (idx < 73728) { W = cl4_w; base = SEG_W1;  N = 128; nbN = 4; mode = 1; }
  else if (idx < 90112) { W = cl4_w; base = SEG_W2;  N = 128; nbN = 4; mode = 2; }
  else                  { W = dec_w; base = SEG_DEC; N = 16;  nbN = 1; mode = 0; }
  int local = idx - base;
  int j    = local & 7;
  int lane = (local >> 3) & 63;
  int frag = local >> 9;
  int nb = frag % nbN;
  int kc = frag / nbN;
  int k = kc * 16 + ((lane >> 5) << 3) + j;
  int n = nb * 32 + (lane & 31);
  float wv;
  if (mode == 0)      wv = (n < N) ? W[k * N + n] : 0.0f;
  else if (mode == 1) wv = W[k * 128 + n] - 0.25f * W[(k + 128) * 128 + n];
  else                wv = 0.25f * W[(k + 128) * 128 + n];
  unsigned short hi = bf16_rn(wv);
  ws[idx]           = hi;
  ws[WS_HALF + idx] = bf16_rn(wv - bf16_f32(hi));
}

// ---------------------------------------------------------------------------
// Standard layer: X[64][K] @ W[K][128] (+T) + b, act, in-place into Xhi/Xlo.
// Wave w owns cols w*32..w*32+31 (distinct B), both 32-row blocks (acc0/acc1).
// B double-buffered from global one kc ahead.
// ---------------------------------------------------------------------------
template <int KC, int ACT, bool ADDT>
__device__ __forceinline__ void layer_std(short* __restrict__ Xhi, short* __restrict__ Xlo,
                                          const unsigned short* __restrict__ whi,
                                          const unsigned short* __restrict__ wlo,
                                          const float* __restrict__ bias,
                                          const float* __restrict__ Tb, int tid) {
  const int l = tid & 63, w = tid >> 6;
  const int lr = l & 31, lh = l >> 5;
  f32x16 acc0 = zero16(), acc1 = zero16();
  const unsigned short* bh = whi + w * 512 + l * 8;
  const unsigned short* bl = wlo + w * 512 + l * 8;
  bf16x8 Bh[2], Bl[2];
  Bh[0] = *(const bf16x8*)(bh);
  Bl[0] = *(const bf16x8*)(bl);
  barrier_lds();  // X (prev epilogue / staging) visible
#pragma unroll
  for (int kc = 0; kc < KC; ++kc) {
    const int cur = kc & 1, nxt = cur ^ 1;
    if (kc + 1 < KC) {
      Bh[nxt] = *(const bf16x8*)(bh + (kc + 1) * 2048);
      Bl[nxt] = *(const bf16x8*)(bl + (kc + 1) * 2048);
    }
    const int g = kc * 2 + lh;
    const int xi0 = xswz(lr, g);
    const int xi1 = xswz(lr + 32, g);
    const bf16x8 ah0 = *(const bf16x8*)&Xhi[xi0];
    const bf16x8 al0 = *(const bf16x8*)&Xlo[xi0];
    const bf16x8 ah1 = *(const bf16x8*)&Xhi[xi1];
    const bf16x8 al1 = *(const bf16x8*)&Xlo[xi1];
    acc0 = MFMA(ah0, Bh[cur], acc0);
    acc1 = MFMA(ah1, Bh[cur], acc1);
    acc0 = MFMA(al0, Bh[cur], acc0);
    acc1 = MFMA(al1, Bh[cur], acc1);
    acc0 = MFMA(ah0, Bl[cur], acc0);
    acc1 = MFMA(ah1, Bl[cur], acc1);
  }
  barrier_lds();  // all waves' X reads done -> in-place write safe
  const int col = w * 32 + lr;
  const int gi = col >> 3, go = col & 7;
  const float bv = ADDT ? 0.0f : bias[col];   // cl4 bias folded into T
#pragma unroll
  for (int mb = 0; mb < 2; ++mb) {
#pragma unroll
    for (int r = 0; r < 16; ++r) {
      const int orow = mb * 32 + (r & 3) + 8 * (r >> 2) + 4 * lh;
      float v = (mb ? acc1[r] : acc0[r]) + bv;
      if (ADDT) v += Tb[(orow >> 2) * 132 + col];
      if (ACT == 0)      v = 1.0f / (1.0f + __expf(-v));  // sigmoid
      else if (ACT == 1) v = fmaxf(v, 0.0f);              // relu
      short h, lo2;
      split1(v, h, lo2);
      const int idx = orow * 128 + ((gi ^ (orow & 15)) << 3) + go;
      Xhi[idx] = h;
      Xlo[idx] = lo2;
    }
  }
}

// T = S @ W2 + cl4_b  (M=16, rows 16..31 of S are zeroed). Wave w -> cols w*32.
__device__ __forceinline__ void tgemm(const short* __restrict__ Shi, const short* __restrict__ Slo,
                                      const unsigned short* __restrict__ whi,
                                      const unsigned short* __restrict__ wlo,
                                      const float* __restrict__ cl4_b,
                                      float* __restrict__ Tb, int tid) {
  const int l = tid & 63, w = tid >> 6;
  const int lr = l & 31, lh = l >> 5;
  f32x16 acc = zero16();
  const unsigned short* bh = whi + SEG_W2 + w * 512 + l * 8;
  const unsigned short* bl = wlo + SEG_W2 + w * 512 + l * 8;
  bf16x8 Bh[2], Bl[2];
  Bh[0] = *(const bf16x8*)(bh);
  Bl[0] = *(const bf16x8*)(bl);
#pragma unroll
  for (int kc = 0; kc < 8; ++kc) {
    const int cur = kc & 1, nxt = cur ^ 1;
    if (kc < 7) {
      Bh[nxt] = *(const bf16x8*)(bh + (kc + 1) * 2048);
      Bl[nxt] = *(const bf16x8*)(bl + (kc + 1) * 2048);
    }
    const int si = xswz(lr, kc * 2 + lh);
    const bf16x8 ah = *(const bf16x8*)&Shi[si];
    const bf16x8 al = *(const bf16x8*)&Slo[si];
    acc = MFMA(ah, Bh[cur], acc);
    acc = MFMA(al, Bh[cur], acc);
    acc = MFMA(ah, Bl[cur], acc);
  }
  const int col = w * 32 + lr;
  const float bv = cl4_b[col];
#pragma unroll
  for (int r = 0; r < 8; ++r) {  // only output rows < 16 are real
    const int prow = (r & 3) + 8 * (r >> 2) + 4 * lh;
    Tb[prow * 132 + col] = acc[r] + bv;
  }
}

// dec: [16 x 512] @ dec_w(pad 32) ; K split across 4 waves; partials -> P.
__device__ __forceinline__ void declayer(const short* __restrict__ Xhi,
                                         const short* __restrict__ Xlo,
                                         const unsigned short* __restrict__ whi,
                                         const unsigned short* __restrict__ wlo,
                                         float* __restrict__ P, int tid) {
  const int l = tid & 63, w = tid >> 6;
  const int lr = l & 31, lh = l >> 5;
  f32x16 acc = zero16();
  const unsigned short* bh = whi + SEG_DEC + w * 4096 + l * 8;
  const unsigned short* bl = wlo + SEG_DEC + w * 4096 + l * 8;
  bf16x8 Bh[2], Bl[2];
  Bh[0] = *(const bf16x8*)(bh);
  Bl[0] = *(const bf16x8*)(bl);
#pragma unroll
  for (int k8 = 0; k8 < 8; ++k8) {
    const int cur = k8 & 1, nxt = cur ^ 1;
    if (k8 < 7) {
      Bh[nxt] = *(const bf16x8*)(bh + (k8 + 1) * 512);
      Bl[nxt] = *(const bf16x8*)(bl + (k8 + 1) * 512);
    }
    bf16x8 ah = {0, 0, 0, 0, 0, 0, 0, 0}, al = {0, 0, 0, 0, 0, 0, 0, 0};
    if (lr < 16) {  // 16 batches only
      const int g128 = (w * 8 + k8) * 2 + lh;     // k/8 in 0..63
      const int xr = lr * 4 + (g128 >> 4);        // batch*4 + agent
      const int xi = xr * 128 + (((g128 & 15) ^ (xr & 15)) << 3);
      ah = *(const bf16x8*)&Xhi[xi];
      al = *(const bf16x8*)&Xlo[xi];
    }
    acc = MFMA(ah, Bh[cur], acc);
    acc = MFMA(al, Bh[cur], acc);
    acc = MFMA(ah, Bl[cur], acc);
  }
  if (lr < 16) {
#pragma unroll
    for (int r = 0; r < 8; ++r) {
      const int prow = (r & 3) + 8 * (r >> 2) + 4 * lh;
      P[w * 272 + prow * 17 + lr] = acc[r];
    }
  }
}

// ---------------------------------------------------------------------------
__global__ __launch_bounds__(256, 2)
void commnet_fwd(const float* __restrict__ O,
                 const float* __restrict__ enc_b, const float* __restrict__ fc1_b,
                 const float* __restrict__ fc2_b, const float* __restrict__ fc3_b,
                 const float* __restrict__ cl4_b, const float* __restrict__ dec_b,
                 const unsigned short* __restrict__ ws, float* __restrict__ out) {
  __shared__ __attribute__((aligned(16))) short Xhi[64 * 128];  // 16 KB
  __shared__ __attribute__((aligned(16))) short Xlo[64 * 128];  // 16 KB
  __shared__ __attribute__((aligned(16))) short Shi[32 * 128];  //  8 KB
  __shared__ __attribute__((aligned(16))) short Slo[32 * 128];  //  8 KB
  __shared__ __attribute__((aligned(16))) float Tb[16 * 132];   //  8.25 KB (also P[4][16][17])

  const int tid = threadIdx.x;

  // ---- stage O [64 x 64] -> split -> swizzled Xhi/Xlo cols 0..63 ----
  {
    const f32x4* Og = (const f32x4*)(O + (long)blockIdx.x * 4096);
#pragma unroll
    for (int it = 0; it < 4; ++it) {
      const int i = it * 256 + tid;       // 0..1023
      const int row = i >> 4;
      const int c4 = (i & 15) << 2;
      f32x4 v = Og[i];
      bf16x4 hv, lv;
#pragma unroll
      for (int j = 0; j < 4; ++j) {
        short hh, ll;
        split1(v[j], hh, ll);
        hv[j] = hh; lv[j] = ll;
      }
      const int bi = row * 128 + (((c4 >> 3) ^ (row & 15)) << 3) + (c4 & 7);
      *(bf16x4*)&Xhi[bi] = hv;
      *(bf16x4*)&Xlo[bi] = lv;
    }
  }

  const unsigned short* whi = ws;
  const unsigned short* wlo = ws + WS_HALF;

  layer_std<4, 0, false>(Xhi, Xlo, whi + SEG_ENC, wlo + SEG_ENC, enc_b, Tb, tid);
  layer_std<8, 1, false>(Xhi, Xlo, whi + SEG_FC1, wlo + SEG_FC1, fc1_b, Tb, tid);
  layer_std<8, 1, false>(Xhi, Xlo, whi + SEG_FC2, wlo + SEG_FC2, fc2_b, Tb, tid);
  layer_std<8, 1, false>(Xhi, Xlo, whi + SEG_FC3, wlo + SEG_FC3, fc3_b, Tb, tid);

  barrier_lds();  // fc3 output visible
  // ---- comm: S[b] = sum of 4 agents (f32 reconstruct), rows 16..31 zeroed ----
  {
    const int b = tid >> 4, cg = tid & 15;
    float s[8];
#pragma unroll
    for (int j = 0; j < 8; ++j) s[j] = 0.0f;
#pragma unroll
    for (int a = 0; a < 4; ++a) {
      const int xi = xswz(b * 4 + a, cg);
      bf16x8 h = *(const bf16x8*)&Xhi[xi];
      bf16x8 lo2 = *(const bf16x8*)&Xlo[xi];
#pragma unroll
      for (int j = 0; j < 8; ++j)
        s[j] += bf16_f32((unsigned short)h[j]) + bf16_f32((unsigned short)lo2[j]);
    }
    bf16x8 sh, sl;
#pragma unroll
    for (int j = 0; j < 8; ++j) {
      short hh, ll;
      split1(s[j], hh, ll);
      sh[j] = hh; sl[j] = ll;
    }
    const int si = xswz(b, cg);
    *(bf16x8*)&Shi[si] = sh;
    *(bf16x8*)&Slo[si] = sl;
    const bf16x8 zz = {0, 0, 0, 0, 0, 0, 0, 0};
    const int zi = xswz(b + 16, cg);
    *(bf16x8*)&Shi[zi] = zz;
    *(bf16x8*)&Slo[zi] = zz;
  }
  barrier_lds();  // S visible

  tgemm(Shi, Slo, whi, wlo, cl4_b, Tb, tid);                      // writes Tb
  layer_std<8, 2, true>(Xhi, Xlo, whi + SEG_W1, wlo + SEG_W1, cl4_b, Tb, tid);

  barrier_lds();  // cl4 X writes visible; everyone done reading Tb
  declayer(Xhi, Xlo, whi, wlo, Tb, tid);                          // writes P (=Tb)
  barrier_lds();  // P visible

  // ---- reduce 4 partials + bias, softmax over 16 cols, store ----
  {
    const int c = tid & 15;
    const int pi = (tid >> 4) * 17 + c;
    float v = Tb[pi] + Tb[272 + pi] + Tb[544 + pi] + Tb[816 + pi] + dec_b[c];
    float m = v;
#pragma unroll
    for (int mk = 1; mk < 16; mk <<= 1) m = fmaxf(m, __shfl_xor(m, mk, 16));
    const float e = __expf(v - m);
    float ssum = e;
#pragma unroll
    for (int mk = 1; mk < 16; mk <<= 1) ssum += __shfl_xor(ssum, mk, 16);
    out[(long)blockIdx.x * 256 + tid] = e / ssum;
  }
}

// ---------------------------------------------------------------------------
extern "C" void kernel_launch(void* const* d_in, const int* in_sizes, int n_in,
                              void* d_out, int out_size, void* d_ws, size_t ws_size,
                              hipStream_t stream) {
  (void)n_in; (void)out_size; (void)ws_size;  // needs ws_size >= 425,984 B
  const float* O     = (const float*)d_in[0];
  const float* enc_w = (const float*)d_in[1];
  const float* enc_b = (const float*)d_in[2];
  const float* fc1_w = (const float*)d_in[3];
  const float* fc1_b = (const float*)d_in[4];
  const float* fc2_w = (const float*)d_in[5];
  const float* fc2_b = (const float*)d_in[6];
  const float* fc3_w = (const float*)d_in[7];
  const float* fc3_b = (const float*)d_in[8];
  const float* cl4_w = (const float*)d_in[9];
  const float* cl4_b = (const float*)d_in[10];
  const float* dec_w = (const float*)d_in[11];
  const float* dec_b = (const float*)d_in[12];
  unsigned short* wsb = (unsigned short*)d_ws;

  prep_weights<<<(WS_HALF + 255) / 256, 256, 0, stream>>>(enc_w, fc1_w, fc2_w, fc3_w,
                                                          cl4_w, dec_w, wsb);
  const int rows   = in_sizes[0] / 64;   // B*A = 262144
  const int blocks = rows / 64;          // 4096
  commnet_fwd<<<blocks, 256, 0, stream>>>(O, enc_b, fc1_b, fc2_b, fc3_b, cl4_b,
                                          dec_b, wsb, (float*)d_out);
}